// Round 1
// baseline (818.115 us; speedup 1.0000x reference)
//
#include <hip/hip_runtime.h>
#include <hip/hip_bf16.h>

// Problem constants (match reference setup_inputs)
#define BS 16384   // B*S tokens
#define HDIM 4096  // hidden dim
#define NE 64      // experts
#define KC 64      // K-chunk per LDS stage
#define TILE_T 64  // tokens per block (K1)

// ---------------------------------------------------------------------------
// K1: logits = A[BS,H] @ W[NE,H]^T, fp32 inputs, fp64 accumulate (accuracy:
// top-C boundary gaps ~1e-3; fp32 accum error ~1e-5 would flip routing bits
// vs the numpy reference). Writes logits token-major (Lg) and expert-major
// (LgT) for the downstream kernels.
// ---------------------------------------------------------------------------
__global__ __launch_bounds__(256) void k1_gemm(const float* __restrict__ A,
                                               const float* __restrict__ W,
                                               double* __restrict__ Lg,
                                               double* __restrict__ LgT) {
    __shared__ __align__(16) float As[KC][68];  // [k][token], +4 pad keeps 16B align
    __shared__ __align__(16) float Ws[KC][68];  // [k][expert]

    const int tid = threadIdx.x;
    const int T0  = blockIdx.x * TILE_T;

    const int q = tid & 15;   // k-quad for staging (k = 4q..4q+3)
    const int r = tid >> 4;   // base row for staging (rows r, r+16, r+32, r+48)

    const int tx = tid & 15;  // expert quad for compute (experts 4tx..4tx+3)
    const int ty = tid >> 4;  // token quad for compute  (tokens 4ty..4ty+3)

    double acc[4][4];
#pragma unroll
    for (int i = 0; i < 4; ++i)
#pragma unroll
        for (int j = 0; j < 4; ++j) acc[i][j] = 0.0;

    float4 ra[4], rw[4];

    // prefetch chunk 0
    {
        const int c0 = 0;
#pragma unroll
        for (int i = 0; i < 4; ++i) {
            const int row = r + 16 * i;
            ra[i] = *(const float4*)&A[(size_t)(T0 + row) * HDIM + c0 + 4 * q];
            rw[i] = *(const float4*)&W[(size_t)row * HDIM + c0 + 4 * q];
        }
    }

    const int NCHUNK = HDIM / KC;
    for (int c = 0; c < NCHUNK; ++c) {
        __syncthreads();
        // store staged regs -> LDS (transposed to [k][row])
#pragma unroll
        for (int i = 0; i < 4; ++i) {
            const int row = r + 16 * i;
            As[4 * q + 0][row] = ra[i].x;
            As[4 * q + 1][row] = ra[i].y;
            As[4 * q + 2][row] = ra[i].z;
            As[4 * q + 3][row] = ra[i].w;
            Ws[4 * q + 0][row] = rw[i].x;
            Ws[4 * q + 1][row] = rw[i].y;
            Ws[4 * q + 2][row] = rw[i].z;
            Ws[4 * q + 3][row] = rw[i].w;
        }
        __syncthreads();
        // prefetch next chunk while computing this one
        if (c + 1 < NCHUNK) {
            const int c0 = (c + 1) * KC;
#pragma unroll
            for (int i = 0; i < 4; ++i) {
                const int row = r + 16 * i;
                ra[i] = *(const float4*)&A[(size_t)(T0 + row) * HDIM + c0 + 4 * q];
                rw[i] = *(const float4*)&W[(size_t)row * HDIM + c0 + 4 * q];
            }
        }
#pragma unroll 8
        for (int k = 0; k < KC; ++k) {
            float4 av = *(const float4*)&As[k][4 * ty];
            float4 wv = *(const float4*)&Ws[k][4 * tx];
            double da[4] = {(double)av.x, (double)av.y, (double)av.z, (double)av.w};
            double dw[4] = {(double)wv.x, (double)wv.y, (double)wv.z, (double)wv.w};
#pragma unroll
            for (int i = 0; i < 4; ++i)
#pragma unroll
                for (int j = 0; j < 4; ++j) acc[i][j] += da[i] * dw[j];
        }
    }

#pragma unroll
    for (int i = 0; i < 4; ++i) {
        const int t = T0 + 4 * ty + i;
#pragma unroll
        for (int j = 0; j < 4; ++j) {
            const int e = 4 * tx + j;
            Lg[(size_t)t * NE + e] = acc[i][j];
            LgT[(size_t)e * BS + t] = acc[i][j];
        }
    }
}

// ---------------------------------------------------------------------------
// K2: per-expert exact top-C. 64-bit radix-select (8 passes, MSB first) on
// order-preserving uint64 keys of the fp64 logits. Tie-break identical to
// jax.lax.top_k: among keys equal to the threshold, lowest token index wins.
// ---------------------------------------------------------------------------
__device__ inline unsigned long long to_key(double d) {
    unsigned long long u = (unsigned long long)__double_as_longlong(d);
    return (u >> 63) ? ~u : (u | 0x8000000000000000ULL);
}

__global__ __launch_bounds__(256) void k2_select(const double* __restrict__ LgT,
                                                 const int* __restrict__ Cptr,
                                                 float* __restrict__ out_map) {
    const int e = blockIdx.x;
    const int tid = threadIdx.x;
    const double* col = LgT + (size_t)e * BS;
    const int C = *Cptr;

    __shared__ unsigned int hist[256];
    __shared__ unsigned long long s_prefix;
    __shared__ int s_remaining;
    __shared__ int scan[256];

    if (tid == 0) { s_prefix = 0ULL; s_remaining = C; }
    __syncthreads();

    for (int p = 7; p >= 0; --p) {
        hist[tid] = 0u;
        __syncthreads();
        const unsigned long long pref = s_prefix;
        const int shift = 8 * p;
        const unsigned long long hmask = (p == 7) ? 0ULL : (~0ULL << (shift + 8));
        for (int i = 0; i < BS / 256; ++i) {
            const int t = i * 256 + tid;
            const unsigned long long key = to_key(col[t]);
            if ((key & hmask) == pref)
                atomicAdd(&hist[(unsigned)(key >> shift) & 255u], 1u);
        }
        __syncthreads();
        if (tid == 0) {
            int rem = s_remaining;
            int d = 255;
            for (; d > 0; --d) {
                const int c = (int)hist[d];
                if (c < rem) rem -= c; else break;
            }
            s_prefix = pref | ((unsigned long long)(unsigned)d << shift);
            s_remaining = rem;
        }
        __syncthreads();
    }

    const unsigned long long T = s_prefix;
    const int need_eq = s_remaining;  // # of ==T keys to take, lowest index first

    // stable marking: thread owns contiguous token range [tid*64, tid*64+64)
    int cnt = 0;
    for (int i = 0; i < 64; ++i) cnt += (to_key(col[tid * 64 + i]) == T);
    scan[tid] = cnt;
    __syncthreads();
    if (tid == 0) {
        int s = 0;
        for (int i = 0; i < 256; ++i) { const int c = scan[i]; scan[i] = s; s += c; }
    }
    __syncthreads();
    int off = scan[tid];
    for (int i = 0; i < 64; ++i) {
        const int t = tid * 64 + i;
        const unsigned long long key = to_key(col[t]);
        float m = 0.f;
        if (key > T) m = 1.f;
        else if (key == T) { if (off < need_eq) m = 1.f; ++off; }
        out_map[(size_t)t * NE + e] = m;
    }
}

// ---------------------------------------------------------------------------
// K3: per-token softmax over 64 experts (one wave per token), mask by
// routing_map, renormalize with +1e-6, write probs, accumulate per-block
// importance partials in fp64.
// ---------------------------------------------------------------------------
__global__ __launch_bounds__(256) void k3_softmax(const double* __restrict__ Lg,
                                                  const float* __restrict__ map,
                                                  float* __restrict__ probs,
                                                  double* __restrict__ imp_partial) {
    const int tid = threadIdx.x;
    const int w = tid >> 6;   // wave id 0..3
    const int e = tid & 63;   // lane = expert
    const int b = blockIdx.x;

    double acc = 0.0;
    for (int it = 0; it < 16; ++it) {
        const int t = b * 64 + it * 4 + w;
        const double x = Lg[(size_t)t * NE + e];
        double mx = x;
#pragma unroll
        for (int off = 32; off; off >>= 1) mx = fmax(mx, __shfl_xor(mx, off));
        const float ev = expf((float)(x - mx));
        float s = ev;
#pragma unroll
        for (int off = 32; off; off >>= 1) s += __shfl_xor(s, off);
        const float p = ev / s;
        const float rm = map[(size_t)t * NE + e];
        const float pm = p * rm;
        float s2 = pm;
#pragma unroll
        for (int off = 32; off; off >>= 1) s2 += __shfl_xor(s2, off);
        const float o = pm / (s2 + 1e-6f);
        probs[(size_t)t * NE + e] = o;
        acc += (double)o;
    }

    __shared__ double buf[4][64];
    buf[w][e] = acc;
    __syncthreads();
    if (w == 0)
        imp_partial[(size_t)b * NE + e] = buf[0][e] + buf[1][e] + buf[2][e] + buf[3][e];
}

// ---------------------------------------------------------------------------
// K4: reduce importance partials, compute aux loss.
// load = exactly C per expert (top-C picks exactly C) -> load_loss == 0.
// ---------------------------------------------------------------------------
__global__ __launch_bounds__(64) void k4_aux(const double* __restrict__ imp_partial,
                                             float* __restrict__ out_aux) {
    const int e = threadIdx.x;  // 64 threads
    double s = 0.0;
    for (int b = 0; b < 256; ++b) s += imp_partial[(size_t)b * NE + e];
    __shared__ double imp[64];
    imp[e] = s;
    __syncthreads();
    if (e == 0) {
        double mean = 0.0;
        for (int i = 0; i < 64; ++i) mean += imp[i];
        mean /= 64.0;
        double var = 0.0;
        for (int i = 0; i < 64; ++i) { const double d = imp[i] - mean; var += d * d; }
        var /= 63.0;  // ddof=1
        const double denom = mean + 1e-6;
        out_aux[0] = (float)(var / (denom * denom));  // + load_loss (==0)
    }
}

extern "C" void kernel_launch(void* const* d_in, const int* in_sizes, int n_in,
                              void* d_out, int out_size, void* d_ws, size_t ws_size,
                              hipStream_t stream) {
    const float* A = (const float*)d_in[0];   // hidden_states [BS, H]
    const float* W = (const float*)d_in[1];   // gate_w [NE, H]
    const int* Cptr = (const int*)d_in[2];    // C = 512

    float* out_probs = (float*)d_out;                      // [BS, NE]
    float* out_map   = out_probs + (size_t)BS * NE;        // [BS, NE]
    float* out_aux   = out_map + (size_t)BS * NE;          // [1]

    double* Lg  = (double*)d_ws;                           // [BS, NE]  8 MB
    double* LgT = Lg + (size_t)BS * NE;                    // [NE, BS]  8 MB
    double* imp_partial = LgT + (size_t)BS * NE;           // [256, NE] 128 KB

    k1_gemm<<<BS / TILE_T, 256, 0, stream>>>(A, W, Lg, LgT);
    k2_select<<<NE, 256, 0, stream>>>(LgT, Cptr, out_map);
    k3_softmax<<<256, 256, 0, stream>>>(Lg, out_map, out_probs, imp_partial);
    k4_aux<<<1, 64, 0, stream>>>(imp_partial, out_aux);
}

// Round 2
// 485.963 us; speedup vs baseline: 1.6835x; 1.6835x over previous
//
#include <hip/hip_runtime.h>
#include <hip/hip_bf16.h>

#define BS 16384   // B*S tokens
#define HDIM 4096  // hidden dim
#define NE 64      // experts
#define KC 64      // K-chunk per LDS stage
#define TILE_T 64  // tokens per block (K1)
#define CAP 512    // max boundary candidates per expert
#define DELTA 2e-3f  // fp32-GEMM error margin (worst-case accum err ~2.5e-4)

// Monotonic sortable key for fp32 (no NaNs in this problem)
__device__ inline unsigned f2key(float f) {
    unsigned u = __float_as_uint(f);
    return (u & 0x80000000u) ? ~u : (u | 0x80000000u);
}
__device__ inline float key2f(unsigned k) {
    unsigned u = (k & 0x80000000u) ? (k ^ 0x80000000u) : ~k;
    return __uint_as_float(u);
}

// ---------------------------------------------------------------------------
// K1: logits = A[BS,H] @ W[NE,H]^T in fp32 with per-64-k fp32 segments folded
// into fp64 (worst-case |err| ~2.5e-4 << DELTA). 1024 threads: 4-way K-split
// within the block (quarter qt owns 16 of each chunk's 64 k-steps) ->
// 16 waves/CU = 4 waves/SIMD. A-tile row-major [tok][k] (b128 stage + b128
// read, conflict-free); W-tile k-major [k][exp] (b128 compute read).
// Writes Lg (fp32 token-major) and KeyT (sortable u32, expert-major).
// ---------------------------------------------------------------------------
__global__ __launch_bounds__(1024, 4) void k1_gemm(const float* __restrict__ A,
                                                   const float* __restrict__ W,
                                                   float* __restrict__ Lg,
                                                   unsigned* __restrict__ KeyT) {
    __shared__ __align__(16) float smem[2 * KC * 68];
    float (*As)[68] = (float(*)[68])smem;             // [tok][k]  64x68
    float (*Ws)[68] = (float(*)[68])(smem + KC * 68); // [k][exp]  64x68

    const int tid = threadIdx.x;
    const int T0  = blockIdx.x * TILE_T;

    const int kq  = tid & 15;   // staging: k-quad (4kq..4kq+3)
    const int row = tid >> 4;   // staging: row 0..63 (token for A, expert for W)

    const int qt   = tid >> 8;       // K-split quarter 0..3
    const int htid = tid & 255;
    const int tx   = htid & 15;      // expert quad
    const int ty   = htid >> 4;      // token quad (0..15)

    float  cacc[4][4];
    double acc[4][4];
#pragma unroll
    for (int i = 0; i < 4; ++i)
#pragma unroll
        for (int j = 0; j < 4; ++j) { cacc[i][j] = 0.f; acc[i][j] = 0.0; }

    float4 ra = *(const float4*)&A[(size_t)(T0 + row) * HDIM + 4 * kq];
    float4 rw = *(const float4*)&W[(size_t)row * HDIM + 4 * kq];

    const int NCHUNK = HDIM / KC;  // 64
    for (int c = 0; c < NCHUNK; ++c) {
        __syncthreads();
        *(float4*)&As[row][4 * kq] = ra;        // contiguous b128 store
        Ws[4 * kq + 0][row] = rw.x;             // transposed scalar stores
        Ws[4 * kq + 1][row] = rw.y;
        Ws[4 * kq + 2][row] = rw.z;
        Ws[4 * kq + 3][row] = rw.w;
        __syncthreads();
        if (c + 1 < NCHUNK) {
            const int c0 = (c + 1) * KC;
            ra = *(const float4*)&A[(size_t)(T0 + row) * HDIM + c0 + 4 * kq];
            rw = *(const float4*)&W[(size_t)row * HDIM + c0 + 4 * kq];
        }
        const int kb = qt * 16;
#pragma unroll
        for (int k4 = 0; k4 < 4; ++k4) {
            const int k0 = kb + 4 * k4;
            float4 a0 = *(const float4*)&As[4 * ty + 0][k0];
            float4 a1 = *(const float4*)&As[4 * ty + 1][k0];
            float4 a2 = *(const float4*)&As[4 * ty + 2][k0];
            float4 a3 = *(const float4*)&As[4 * ty + 3][k0];
            float4 w0 = *(const float4*)&Ws[k0 + 0][4 * tx];
            float4 w1 = *(const float4*)&Ws[k0 + 1][4 * tx];
            float4 w2 = *(const float4*)&Ws[k0 + 2][4 * tx];
            float4 w3 = *(const float4*)&Ws[k0 + 3][4 * tx];
            const float* ap[4] = {(const float*)&a0, (const float*)&a1,
                                  (const float*)&a2, (const float*)&a3};
            const float* wp[4] = {(const float*)&w0, (const float*)&w1,
                                  (const float*)&w2, (const float*)&w3};
#pragma unroll
            for (int s = 0; s < 4; ++s)
#pragma unroll
                for (int i = 0; i < 4; ++i)
#pragma unroll
                    for (int j = 0; j < 4; ++j)
                        cacc[i][j] = fmaf(ap[i][s], wp[s][j], cacc[i][j]);
        }
        if ((c & 3) == 3) {  // fold 64-product fp32 segment into fp64
#pragma unroll
            for (int i = 0; i < 4; ++i)
#pragma unroll
                for (int j = 0; j < 4; ++j) { acc[i][j] += (double)cacc[i][j]; cacc[i][j] = 0.f; }
        }
    }

    // Combine the 4 quarters' fp64 partials via LDS (sequential tree).
    double* dbuf = (double*)smem;  // 4352 doubles available, need 4096
    __syncthreads();
    if (qt == 3) {
#pragma unroll
        for (int i = 0; i < 4; ++i)
#pragma unroll
            for (int j = 0; j < 4; ++j) dbuf[htid * 16 + i * 4 + j] = acc[i][j];
    }
    __syncthreads();
    if (qt == 2) {
#pragma unroll
        for (int i = 0; i < 4; ++i)
#pragma unroll
            for (int j = 0; j < 4; ++j) dbuf[htid * 16 + i * 4 + j] += acc[i][j];
    }
    __syncthreads();
    if (qt == 1) {
#pragma unroll
        for (int i = 0; i < 4; ++i)
#pragma unroll
            for (int j = 0; j < 4; ++j) dbuf[htid * 16 + i * 4 + j] += acc[i][j];
    }
    __syncthreads();
    if (qt == 0) {
        float f[4][4];
#pragma unroll
        for (int i = 0; i < 4; ++i)
#pragma unroll
            for (int j = 0; j < 4; ++j)
                f[i][j] = (float)(acc[i][j] + dbuf[htid * 16 + i * 4 + j]);
#pragma unroll
        for (int i = 0; i < 4; ++i) {
            const int t = T0 + 4 * ty + i;
            float4 o = {f[i][0], f[i][1], f[i][2], f[i][3]};
            *(float4*)&Lg[(size_t)t * NE + 4 * tx] = o;
        }
#pragma unroll
        for (int j = 0; j < 4; ++j) {
            const int e = 4 * tx + j;
            uint4 kv = {f2key(f[0][j]), f2key(f[1][j]), f2key(f[2][j]), f2key(f[3][j])};
            *(uint4*)&KeyT[(size_t)e * BS + T0 + 4 * ty] = kv;
        }
    }
}

// ---------------------------------------------------------------------------
// K2: per-expert C-th-largest fp32 key via 4-pass radix (parallel suffix
// scan), then classify: key > khi -> definite-in; klo<=key<=khi -> candidate
// (appended for fp64 resolution). Also zeroes the winner bitmap.
// ---------------------------------------------------------------------------
__global__ __launch_bounds__(1024) void k2_select(const unsigned* __restrict__ KeyT,
                                                  const int* __restrict__ Cptr,
                                                  unsigned* __restrict__ khi_g,
                                                  int* __restrict__ needed_g,
                                                  int* __restrict__ ncand_g,
                                                  int* __restrict__ cand_g,
                                                  unsigned* __restrict__ win_g) {
    const int e = blockIdx.x;
    const int tid = threadIdx.x;
    const unsigned* col = KeyT + (size_t)e * BS;
    const int C = *Cptr;

    __shared__ int hist[256];
    __shared__ int sfx[256];
    __shared__ unsigned s_pref;
    __shared__ int s_rem, s_nc, s_nd;

    if (tid == 0) { s_pref = 0u; s_rem = C; s_nc = 0; s_nd = 0; }
    for (int i = tid; i < CAP; i += 1024) win_g[(size_t)e * CAP + i] = 0u;
    __syncthreads();

    for (int p = 3; p >= 0; --p) {
        if (tid < 256) hist[tid] = 0;
        __syncthreads();
        const int shift = 8 * p;
        const unsigned maskhi = (p == 3) ? 0u : (0xFFFFFFFFu << (shift + 8));
        const unsigned pref = s_pref;
        const int rem = s_rem;
        for (int i = 0; i < BS / 1024; ++i) {
            const unsigned k = col[i * 1024 + tid];
            if ((k & maskhi) == pref) atomicAdd(&hist[(k >> shift) & 255u], 1);
        }
        __syncthreads();
        if (tid < 256) sfx[tid] = hist[tid];
        __syncthreads();
        for (int off = 1; off < 256; off <<= 1) {
            int v = 0;
            if (tid < 256 && tid + off < 256) v = sfx[tid + off];
            __syncthreads();
            if (tid < 256) sfx[tid] += v;
            __syncthreads();
        }
        if (tid < 256) {
            const int Sd = sfx[tid];
            const int Sd1 = (tid == 255) ? 0 : sfx[tid + 1];
            if (Sd >= rem && Sd1 < rem) {  // exactly one thread
                s_pref = pref | ((unsigned)tid << shift);
                s_rem = rem - Sd1;
            }
        }
        __syncthreads();
    }

    const float vT = key2f(s_pref);
    const unsigned khi = f2key(vT + DELTA);
    const unsigned klo = f2key(vT - DELTA);

    for (int i = 0; i < BS / 1024; ++i) {
        const int t = i * 1024 + tid;
        const unsigned k = col[t];
        if (k > khi) atomicAdd(&s_nd, 1);
        else if (k >= klo) {
            const int pos = atomicAdd(&s_nc, 1);
            if (pos < CAP) cand_g[(size_t)e * CAP + pos] = t;
        }
    }
    __syncthreads();
    if (tid == 0) {
        khi_g[e] = khi;
        needed_g[e] = C - s_nd;
        ncand_g[e] = (s_nc < CAP) ? s_nc : CAP;
    }
}

// ---------------------------------------------------------------------------
// K2b: exact fp64 dot for each boundary candidate; winners = top-'needed'
// by (fp64 value desc, index asc) -> set bits in winner bitmap.
// ---------------------------------------------------------------------------
__global__ __launch_bounds__(256) void k2b_resolve(const float* __restrict__ A,
                                                   const float* __restrict__ W,
                                                   const int* __restrict__ needed_g,
                                                   const int* __restrict__ ncand_g,
                                                   const int* __restrict__ cand_g,
                                                   unsigned* __restrict__ win_g) {
    const int e = blockIdx.x;
    const int tid = threadIdx.x;
    int n = ncand_g[e]; if (n > CAP) n = CAP;
    int need = needed_g[e];
    if (need > n) need = n;
    if (need < 0) need = 0;

    __shared__ double sval[CAP];
    __shared__ int sidx[CAP];
    __shared__ unsigned char chosen[CAP];
    __shared__ double wred[4];

    for (int i = tid; i < CAP; i += 256) {
        sidx[i] = (i < n) ? cand_g[(size_t)e * CAP + i] : 0;
        chosen[i] = 0;
    }
    __syncthreads();

    const float* Wr = W + (size_t)e * HDIM;
    for (int c = 0; c < n; ++c) {
        const int t = sidx[c];
        const float* Ar = A + (size_t)t * HDIM;
        double ps = 0.0;
#pragma unroll
        for (int j = 0; j < HDIM / 256; ++j)
            ps += (double)Ar[j * 256 + tid] * (double)Wr[j * 256 + tid];
#pragma unroll
        for (int off = 32; off; off >>= 1) ps += __shfl_xor(ps, off);
        if ((tid & 63) == 0) wred[tid >> 6] = ps;
        __syncthreads();
        if (tid == 0) sval[c] = wred[0] + wred[1] + wred[2] + wred[3];
        __syncthreads();
    }

    if (tid == 0) {
        for (int s = 0; s < need; ++s) {
            int best = -1;
            for (int c = 0; c < n; ++c) {
                if (chosen[c]) continue;
                if (best < 0 || sval[c] > sval[best] ||
                    (sval[c] == sval[best] && sidx[c] < sidx[best]))
                    best = c;
            }
            chosen[best] = 1;
            const int t = sidx[best];
            win_g[(size_t)e * CAP + (t >> 5)] |= (1u << (t & 31));
        }
    }
}

// ---------------------------------------------------------------------------
// K3: per-token softmax (fp32), map = definite (key>khi) | winner bit,
// mask+renormalize, write probs+map, fp64 importance partials.
// ---------------------------------------------------------------------------
__global__ __launch_bounds__(256) void k3_softmax(const float* __restrict__ Lg,
                                                  const unsigned* __restrict__ khi_g,
                                                  const unsigned* __restrict__ win_g,
                                                  float* __restrict__ probs,
                                                  float* __restrict__ out_map,
                                                  double* __restrict__ imp_partial) {
    const int tid = threadIdx.x;
    const int w = tid >> 6;
    const int e = tid & 63;
    const int b = blockIdx.x;

    __shared__ unsigned skhi[64];
    __shared__ double buf[4][64];
    if (tid < 64) skhi[tid] = khi_g[tid];
    __syncthreads();

    double accim = 0.0;
    for (int it = 0; it < 16; ++it) {
        const int t = b * 64 + it * 4 + w;
        const float x = Lg[(size_t)t * NE + e];
        const unsigned key = f2key(x);
        float m;
        if (key > skhi[e]) m = 1.f;
        else m = ((win_g[(size_t)e * CAP + (t >> 5)] >> (t & 31)) & 1u) ? 1.f : 0.f;

        float mx = x;
#pragma unroll
        for (int off = 32; off; off >>= 1) mx = fmaxf(mx, __shfl_xor(mx, off));
        const float ev = expf(x - mx);
        float s = ev;
#pragma unroll
        for (int off = 32; off; off >>= 1) s += __shfl_xor(s, off);
        const float p = ev / s;
        const float pm = p * m;
        float s2 = pm;
#pragma unroll
        for (int off = 32; off; off >>= 1) s2 += __shfl_xor(s2, off);
        const float o = pm / (s2 + 1e-6f);
        probs[(size_t)t * NE + e] = o;
        out_map[(size_t)t * NE + e] = m;
        accim += (double)o;
    }
    buf[w][e] = accim;
    __syncthreads();
    if (w == 0)
        imp_partial[(size_t)b * NE + e] = buf[0][e] + buf[1][e] + buf[2][e] + buf[3][e];
}

// ---------------------------------------------------------------------------
// K4: aux loss. load == C exactly per expert -> load_loss == 0.
// ---------------------------------------------------------------------------
__global__ __launch_bounds__(64) void k4_aux(const double* __restrict__ imp_partial,
                                             float* __restrict__ out_aux) {
    const int e = threadIdx.x;
    double s = 0.0;
    for (int b = 0; b < 256; ++b) s += imp_partial[(size_t)b * NE + e];
    __shared__ double imp[64];
    imp[e] = s;
    __syncthreads();
    if (e == 0) {
        double mean = 0.0;
        for (int i = 0; i < 64; ++i) mean += imp[i];
        mean /= 64.0;
        double var = 0.0;
        for (int i = 0; i < 64; ++i) { const double d = imp[i] - mean; var += d * d; }
        var /= 63.0;
        const double denom = mean + 1e-6;
        out_aux[0] = (float)(var / (denom * denom));
    }
}

extern "C" void kernel_launch(void* const* d_in, const int* in_sizes, int n_in,
                              void* d_out, int out_size, void* d_ws, size_t ws_size,
                              hipStream_t stream) {
    const float* A = (const float*)d_in[0];
    const float* W = (const float*)d_in[1];
    const int* Cptr = (const int*)d_in[2];

    float* out_probs = (float*)d_out;
    float* out_map   = out_probs + (size_t)BS * NE;
    float* out_aux   = out_map + (size_t)BS * NE;

    char* wsb = (char*)d_ws;
    float*    Lg      = (float*)wsb;                          // 4 MB
    unsigned* KeyT    = (unsigned*)(wsb + (4u << 20));        // 4 MB
    unsigned* khi_g   = (unsigned*)(wsb + (8u << 20));        // 256 B
    int*      needed  = (int*)(wsb + (8u << 20) + 1024);      // 256 B
    int*      ncand   = (int*)(wsb + (8u << 20) + 2048);      // 256 B
    int*      cand    = (int*)(wsb + (8u << 20) + 4096);      // 128 KB
    unsigned* winners = (unsigned*)(wsb + (8u << 20) + (256u << 10));  // 128 KB
    double*   imp     = (double*)(wsb + (8u << 20) + (512u << 10));    // 128 KB

    k1_gemm<<<BS / TILE_T, 1024, 0, stream>>>(A, W, Lg, KeyT);
    k2_select<<<NE, 1024, 0, stream>>>(KeyT, Cptr, khi_g, needed, ncand, cand, winners);
    k2b_resolve<<<NE, 256, 0, stream>>>(A, W, needed, ncand, cand, winners);
    k3_softmax<<<256, 256, 0, stream>>>(Lg, khi_g, winners, out_probs, out_map, imp);
    k4_aux<<<1, 64, 0, stream>>>(imp, out_aux);
}